// Round 10
// baseline (2461.186 us; speedup 1.0000x reference)
//
#include <hip/hip_runtime.h>
#include <math.h>

#define KB       4            // blocks (1 per CU)
#define NTHREADS 256
#define NW       4            // waves per block
#define HID      4096
#define HB       (HID / KB)   // 1024 neurons per block
#define NPT      4            // neurons per thread
#define TT       1000
#define PP       16
#define SLOTW    32           // u64 stride per wave-line (256 B)
#define NLINES   (KB * NW)    // 16 published lines

#define BETA 0.9f
#define THRV 0.5f
#define DTV  0.005f

// DPP cross-lane: quad_perm {1,0,3,2}=0xB1 (lane^1), {2,3,0,1}=0x4E (lane^2),
// row_ror:8 = 0x128 (lane^8 within row-of-16). All VALU-pipe (no DS).
template<int CTRL>
__device__ __forceinline__ float dppx(float v) {
    return __int_as_float(__builtin_amdgcn_update_dpp(
        0, __float_as_int(v), CTRL, 0xF, 0xF, true));
}

__device__ __forceinline__ unsigned long long AL(const unsigned long long* p) {
    return __hip_atomic_load(p, __ATOMIC_RELAXED, __HIP_MEMORY_SCOPE_AGENT);
}
__device__ __forceinline__ void AS(unsigned long long* p, unsigned long long v) {
    __hip_atomic_store(p, v, __ATOMIC_RELAXED, __HIP_MEMORY_SCOPE_AGENT);
}

// ---- pipelined poll primitives ----------------------------------------------
// 16 agent-scope loads (one per published line), saddr + voffset + imm offsets.
// "+v" keeps batch registers live across steps so in-flight stragglers can
// never clobber a reallocated vreg (drained passively before next reissue).
#define ISSUE16(B) asm volatile( \
    "global_load_dwordx2 %0,  %16, %17 sc1\n\t" \
    "global_load_dwordx2 %1,  %16, %17 offset:256 sc1\n\t" \
    "global_load_dwordx2 %2,  %16, %17 offset:512 sc1\n\t" \
    "global_load_dwordx2 %3,  %16, %17 offset:768 sc1\n\t" \
    "global_load_dwordx2 %4,  %16, %17 offset:1024 sc1\n\t" \
    "global_load_dwordx2 %5,  %16, %17 offset:1280 sc1\n\t" \
    "global_load_dwordx2 %6,  %16, %17 offset:1536 sc1\n\t" \
    "global_load_dwordx2 %7,  %16, %17 offset:1792 sc1\n\t" \
    "global_load_dwordx2 %8,  %16, %17 offset:2048 sc1\n\t" \
    "global_load_dwordx2 %9,  %16, %17 offset:2304 sc1\n\t" \
    "global_load_dwordx2 %10, %16, %17 offset:2560 sc1\n\t" \
    "global_load_dwordx2 %11, %16, %17 offset:2816 sc1\n\t" \
    "global_load_dwordx2 %12, %16, %17 offset:3072 sc1\n\t" \
    "global_load_dwordx2 %13, %16, %17 offset:3328 sc1\n\t" \
    "global_load_dwordx2 %14, %16, %17 offset:3584 sc1\n\t" \
    "global_load_dwordx2 %15, %16, %17 offset:3840 sc1" \
    : "+v"(B[0]),  "+v"(B[1]),  "+v"(B[2]),  "+v"(B[3]), \
      "+v"(B[4]),  "+v"(B[5]),  "+v"(B[6]),  "+v"(B[7]), \
      "+v"(B[8]),  "+v"(B[9]),  "+v"(B[10]), "+v"(B[11]), \
      "+v"(B[12]), "+v"(B[13]), "+v"(B[14]), "+v"(B[15]) \
    : "v"(vo), "s"(slots) : "memory")

// vmcnt(16): with 2 batches (32 loads) + older prefetch/store ops outstanding,
// this guarantees the OLDEST batch has fully landed (in-order decrement, m135).
#define WAIT16 do { asm volatile("s_waitcnt vmcnt(16)" ::: "memory"); \
                    __builtin_amdgcn_sched_barrier(0); } while (0)

#define PAY(v)   __uint_as_float((unsigned)(v))
#define TAGOK(v) ((unsigned)((v) >> 32) == tw)
#define CHECK16(B) (TAGOK(B[0])&TAGOK(B[1])&TAGOK(B[2])&TAGOK(B[3])& \
                    TAGOK(B[4])&TAGOK(B[5])&TAGOK(B[6])&TAGOK(B[7])& \
                    TAGOK(B[8])&TAGOK(B[9])&TAGOK(B[10])&TAGOK(B[11])& \
                    TAGOK(B[12])&TAGOK(B[13])&TAGOK(B[14])&TAGOK(B[15]))
// canonical balanced tree over line index 0..15 — identical in every wave/block
#define TREE16(B) ((((PAY(B[0])+PAY(B[1]))+(PAY(B[2])+PAY(B[3]))) + \
                    ((PAY(B[4])+PAY(B[5]))+(PAY(B[6])+PAY(B[7])))) + \
                   (((PAY(B[8])+PAY(B[9]))+(PAY(B[10])+PAY(B[11]))) + \
                    ((PAY(B[12])+PAY(B[13]))+(PAY(B[14])+PAY(B[15])))))

__global__ __launch_bounds__(NTHREADS, 1)
void snn_kernel(const float* __restrict__ x,
                const float* __restrict__ noise,
                const float* __restrict__ Win,
                const float* __restrict__ Wout,
                const float* __restrict__ pin,
                const float* __restrict__ pout,
                const float* __restrict__ lvec,
                const float* __restrict__ stdv,
                float* __restrict__ out,
                unsigned long long* __restrict__ slots)
{
    const int b    = blockIdx.x;
    const int tid  = threadIdx.x;
    const int wave = tid >> 6;
    const int lane = tid & 63;
    const int Lown = b * NW + wave;        // this wave's published line
    const int h0   = b * HB + tid * NPT;   // four consecutive neurons per thread

    const bool lb0 = (lane & 1) != 0;
    const bool lb1 = (lane & 2) != 0;
    const bool lb2 = (lane & 4) != 0;
    const bool lb3 = (lane & 8) != 0;

    __shared__ float ubuf[NW][16];         // per-wave u broadcast (wave-local, no barrier)

    // ---------------- parameter load (once) ----------------
    float lv[PP];
    #pragma unroll
    for (int p = 0; p < PP; p += 4) {
        float4 t4 = *(const float4*)&lvec[p];
        lv[p] = t4.x; lv[p+1] = t4.y; lv[p+2] = t4.z; lv[p+3] = t4.w;
    }
    float pl[NPT][PP], po[NPT][PP];
    #pragma unroll
    for (int j = 0; j < NPT; ++j) {
        #pragma unroll
        for (int p = 0; p < PP; p += 4) {
            float4 a = *(const float4*)&pin[(h0+j)*PP + p];
            pl[j][p]   = a.x*lv[p];   pl[j][p+1] = a.y*lv[p+1];
            pl[j][p+2] = a.z*lv[p+2]; pl[j][p+3] = a.w*lv[p+3];
            float4 e4 = *(const float4*)&pout[(h0+j)*PP + p];
            po[j][p]   = e4.x; po[j][p+1] = e4.y;
            po[j][p+2] = e4.z; po[j][p+3] = e4.w;
        }
    }
    float win[NPT][6];
    #pragma unroll
    for (int j = 0; j < NPT; ++j) {
        const float2* wr = (const float2*)&Win[(h0+j)*6];
        float2 wA = wr[0], wB = wr[1], wC = wr[2];
        win[j][0]=wA.x; win[j][1]=wA.y; win[j][2]=wB.x;
        win[j][3]=wB.y; win[j][4]=wC.x; win[j][5]=wC.y;
    }
    float4 woa = *(const float4*)&Wout[h0];        // Wout[0][h0..h0+3]
    float4 wob = *(const float4*)&Wout[HID + h0];  // Wout[1][h0..h0+3]

    float4 sd4 = *(const float4*)&stdv[h0];
    float dd[NPT], sg[NPT];
    {
        float sdv[4] = { sd4.x, sd4.y, sd4.z, sd4.w };
        #pragma unroll
        for (int j = 0; j < NPT; ++j) {
            float sig = 1.f / (1.f + expf(-sdv[j]));
            float tau = sig * 0.03f + 0.02f;
            dd[j] = expf(-DTV / tau);
            sg[j] = DTV / (tau * 0.002f);
        }
    }
    const float DECAY_R = expf(-2.5f);
    const float DTE     = DTV * DECAY_R;

    // ---------------- state ----------------
    float mem[NPT], rr[NPT], ss[NPT];
    float pre[NPT], rlin[NPT], slin[NPT];
    float palin[PP], yalin = 0.f, yblin = 0.f;
    #pragma unroll
    for (int j = 0; j < NPT; ++j) { mem[j]=0.f; rr[j]=0.f; ss[j]=0.f; }
    #pragma unroll
    for (int p = 0; p < PP; ++p) palin[p] = 0.f;

    const float2* x2 = (const float2*)x;
    float4 nz = *(const float4*)&noise[h0];           // t = 0
    float2 xa = x2[0], xb = x2[1], xc = x2[2];

    float uu[16];
    #pragma unroll
    for (int p = 0; p < 16; ++p) uu[p] = 0.f;

    float bpart = 0.f;                 // butterfly output for next publish
    unsigned long long bat0[16] = {0}, bat1[16] = {0};
    int use_pipe = 1;

    for (int t = 0; t <= TT; ++t) {
        const int par = t & 1;

        // ---- publish tag t (pa of r_{t-1}, computed at end of prev iter) ----
        if (t > 0 && lane < 18) {
            union { float f; unsigned u; } cv; cv.f = bpart;
            unsigned long long pk = ((unsigned long long)(unsigned)t << 32)
                                  | (unsigned long long)cv.u;
            AS(&slots[(size_t)(par*NLINES + Lown)*SLOTW + lane], pk);
        }

        // ---- visibility window: u-independent work for step t ----
        if (t < TT) {
            float nzv[4] = { nz.x, nz.y, nz.z, nz.w };
            #pragma unroll
            for (int j = 0; j < NPT; ++j) {
                float xw = win[j][0]*xa.x + win[j][1]*xa.y
                         + win[j][2]*xb.x + win[j][3]*xb.y
                         + win[j][4]*xc.x + win[j][5]*xc.y;
                float rst = (mem[j] - THRV > 0.f) ? THRV : 0.f;
                pre[j]  = BETA*mem[j] + xw + nzv[j] / 10.0f - rst;
                rlin[j] = dd[j]*rr[j] + DTE*ss[j];
                slin[j] = DECAY_R*ss[j];
            }
            #pragma unroll
            for (int p = 0; p < PP; ++p)
                palin[p] = (po[0][p]*rlin[0] + po[1][p]*rlin[1])
                         + (po[2][p]*rlin[2] + po[3][p]*rlin[3]);
            yalin = (woa.x*rlin[0]+woa.y*rlin[1]) + (woa.z*rlin[2]+woa.w*rlin[3]);
            yblin = (wob.x*rlin[0]+wob.y*rlin[1]) + (wob.z*rlin[2]+wob.w*rlin[3]);
        }

        // ---- poll all 16 tagged lines (pipelined, 2 batches in flight) ----
        if (t > 0 && (t < TT || b == 0)) {
            const unsigned tw = (unsigned)t;
            const unsigned vo = (unsigned)(par * (NLINES*SLOTW*8) + lane*8);
            const bool act = (lane < 18);
            float total = 0.f;
            int got = act ? 0 : 1;

            if (use_pipe) {
                if (act) { ISSUE16(bat0); ISSUE16(bat1); }
                const int CAP = (t == 1) ? 512 : 128;   // stage-pairs
                int sp = 0, alldone = 0;
                for (;;) {
                    WAIT16;
                    if (act && !got) {
                        if (CHECK16(bat0)) { total = TREE16(bat0); got = 1; }
                        else ISSUE16(bat0);
                    }
                    alldone = __all(got); if (alldone) break;
                    WAIT16;
                    if (act && !got) {
                        if (CHECK16(bat1)) { total = TREE16(bat1); got = 1; }
                        else ISSUE16(bat1);
                    }
                    alldone = __all(got); if (alldone) break;
                    if (++sp >= CAP) break;
                }
                if (!alldone) {
                    asm volatile("s_waitcnt vmcnt(0)" ::: "memory");
                    use_pipe = 0;                       // sticky fallback
                }
            }
            if (!use_pipe && act && !got) {
                const unsigned long long* bp =
                    slots + (size_t)par*NLINES*SLOTW + lane;
                int sp2 = 0;
                for (;;) {
                    unsigned long long v[16]; int ok = 1;
                    #pragma unroll
                    for (int L = 0; L < 16; ++L) {
                        v[L] = AL(bp + (size_t)L*SLOTW);
                        ok &= ((unsigned)(v[L] >> 32) == tw);
                    }
                    if (ok) { total = TREE16(v); break; }
                    if (++sp2 >= (1 << 20)) break;
                }
            }

            if (lane < 16) ubuf[wave][lane] = total;
            if (b == 0 && wave == 0 && lane >= 16 && lane < 18)
                out[(t-1)*2 + (lane - 16)] = total;     // y[t-1]

            float4 u0 = *(const float4*)&ubuf[wave][0];
            float4 u1 = *(const float4*)&ubuf[wave][4];
            float4 u2 = *(const float4*)&ubuf[wave][8];
            float4 u3 = *(const float4*)&ubuf[wave][12];
            uu[0]=u0.x; uu[1]=u0.y; uu[2]=u0.z; uu[3]=u0.w;
            uu[4]=u1.x; uu[5]=u1.y; uu[6]=u1.z; uu[7]=u1.w;
            uu[8]=u2.x; uu[9]=u2.y; uu[10]=u2.z; uu[11]=u2.w;
            uu[12]=u3.x; uu[13]=u3.y; uu[14]=u3.z; uu[15]=u3.w;
        }

        // ---- step t update + next projection + butterfly ----
        if (t < TT) {
            float rs[NPT];
            #pragma unroll
            for (int j = 0; j < NPT; ++j) {
                float ra  = pl[j][0]*uu[0];
                float rb_ = pl[j][8]*uu[8];
                #pragma unroll
                for (int p = 1; p < 8; ++p) {
                    ra  += pl[j][p]*uu[p];
                    rb_ += pl[j][p+8]*uu[p+8];
                }
                mem[j] = pre[j] + (ra + rb_);
                bool spk = (mem[j] - THRV > 0.f);
                float rspk = spk ? DTV*sg[j] : 0.f;
                ss[j] = slin[j] + (spk ? sg[j] : 0.f);
                rr[j] = rlin[j] + rspk;
                rs[j] = rspk;
            }
            float pa[18];
            #pragma unroll
            for (int p = 0; p < PP; ++p)
                pa[p] = palin[p] + ((po[0][p]*rs[0] + po[1][p]*rs[1])
                                 +  (po[2][p]*rs[2] + po[3][p]*rs[3]));
            pa[16] = yalin + ((woa.x*rs[0]+woa.y*rs[1]) + (woa.z*rs[2]+woa.w*rs[3]));
            pa[17] = yblin + ((wob.x*rs[0]+wob.y*rs[1]) + (wob.z*rs[2]+wob.w*rs[3]));

            // reduce-scatter butterfly: lane ends with u[lane&15] / y[lane&1]
            float a1[8], yv;
            #pragma unroll
            for (int k = 0; k < 8; ++k) {
                float keep = lb0 ? pa[2*k+1] : pa[2*k];
                float send = lb0 ? pa[2*k]   : pa[2*k+1];
                a1[k] = keep + dppx<0xB1>(send);          // xor1 (DPP)
            }
            {
                float keep = lb0 ? pa[17] : pa[16];
                float send = lb0 ? pa[16] : pa[17];
                yv = keep + dppx<0xB1>(send);
            }
            float a2[4];
            #pragma unroll
            for (int k = 0; k < 4; ++k) {
                float keep = lb1 ? a1[2*k+1] : a1[2*k];
                float send = lb1 ? a1[2*k]   : a1[2*k+1];
                a2[k] = keep + dppx<0x4E>(send);          // xor2 (DPP)
            }
            yv += dppx<0x4E>(yv);
            float a3[2];
            #pragma unroll
            for (int k = 0; k < 2; ++k) {
                float keep = lb2 ? a2[2*k+1] : a2[2*k];
                float send = lb2 ? a2[2*k]   : a2[2*k+1];
                a3[k] = keep + __shfl_xor(send, 4, 64);   // xor4 (DS)
            }
            yv += __shfl_xor(yv, 4, 64);
            float uv;
            {
                float keep = lb3 ? a3[1] : a3[0];
                float send = lb3 ? a3[0] : a3[1];
                uv = keep + dppx<0x128>(send);            // xor8 (DPP row_ror:8)
            }
            yv += dppx<0x128>(yv);
            uv += __shfl_xor(uv, 16, 64);                 // xor16 (DS)
            uv += __shfl_xor(uv, 32, 64);                 // xor32 (DS)
            yv += __shfl_xor(yv, 16, 64);
            yv += __shfl_xor(yv, 32, 64);
            bpart = (lane < 16) ? uv : yv;

            // prefetch next step's inputs (completes during next publish/vis)
            if (t < TT - 1) {
                const int tn = t + 1;
                nz = *(const float4*)&noise[tn * HID + h0];
                xa = x2[tn*3]; xb = x2[tn*3+1]; xc = x2[tn*3+2];
            }
        }
    }
}

extern "C" void kernel_launch(void* const* d_in, const int* in_sizes, int n_in,
                              void* d_out, int out_size, void* d_ws, size_t ws_size,
                              hipStream_t stream)
{
    const float* x     = (const float*)d_in[0];
    const float* noise = (const float*)d_in[1];
    const float* Win   = (const float*)d_in[2];
    const float* Wout  = (const float*)d_in[3];
    const float* pin   = (const float*)d_in[4];
    const float* pout  = (const float*)d_in[5];
    const float* l     = (const float*)d_in[6];
    const float* stdv  = (const float*)d_in[7];
    float* out = (float*)d_out;
    unsigned long long* slots = (unsigned long long*)d_ws;   // 2*16*32*8 = 8 KB

    hipLaunchKernelGGL(snn_kernel, dim3(KB), dim3(NTHREADS), 0, stream,
                       x, noise, Win, Wout, pin, pout, l, stdv,
                       out, slots);
}

// Round 11
// 1608.890 us; speedup vs baseline: 1.5297x; 1.5297x over previous
//
#include <hip/hip_runtime.h>
#include <math.h>

#define KB       4            // blocks (one per CU)
#define NTHREADS 256
#define NW       4            // waves per block
#define HID      4096
#define HB       (HID / KB)   // 1024 neurons per block
#define NPT      4            // neurons per thread
#define TT       1000
#define PP       16
#define SLOTW    32           // u64 stride per block-slot (256B, line-aligned)

#define BETA 0.9f
#define THRV 0.5f
#define DTV  0.005f

// DPP cross-lane: quad_perm {1,0,3,2}=0xB1 (lane^1), {2,3,0,1}=0x4E (lane^2),
// row_ror:8 = 0x128 (lane^8 within row-of-16). All VALU-pipe (no DS).
template<int CTRL>
__device__ __forceinline__ float dppx(float v) {
    return __int_as_float(__builtin_amdgcn_update_dpp(
        0, __float_as_int(v), CTRL, 0xF, 0xF, true));
}

__device__ __forceinline__ unsigned long long AL(const unsigned long long* p) {
    return __hip_atomic_load(p, __ATOMIC_RELAXED, __HIP_MEMORY_SCOPE_AGENT);
}
__device__ __forceinline__ void AS(unsigned long long* p, unsigned long long v) {
    __hip_atomic_store(p, v, __ATOMIC_RELAXED, __HIP_MEMORY_SCOPE_AGENT);
}

__global__ __launch_bounds__(NTHREADS, 1)
void snn_kernel(const float* __restrict__ x,
                const float* __restrict__ noise,
                const float* __restrict__ Win,
                const float* __restrict__ Wout,
                const float* __restrict__ pin,
                const float* __restrict__ pout,
                const float* __restrict__ lvec,
                const float* __restrict__ stdv,
                float* __restrict__ ypart,
                unsigned long long* __restrict__ slots)
{
    const int b    = blockIdx.x;
    const int tid  = threadIdx.x;
    const int wave = tid >> 6;
    const int lane = tid & 63;
    const int h0   = b * HB + tid * NPT;   // four consecutive neurons per thread

    const bool lb0 = (lane & 1) != 0;
    const bool lb1 = (lane & 2) != 0;
    const bool lb2 = (lane & 4) != 0;
    const bool lb3 = (lane & 8) != 0;

    // remote block indices in ascending order (for canonical sum tree)
    const int rbA = (b == 0) ? 1 : 0;
    const int rbB = (b <= 1) ? 2 : 1;
    const int rbC = (b <= 2) ? 3 : 2;

    __shared__ float part[NW][20];       // per-wave butterfly results (u:0-15, y:16-17)
    __shared__ float ubuf[NW][16];       // per-wave u broadcast area

    // ---------------- parameter load (once) ----------------
    float lv[PP];
    #pragma unroll
    for (int p = 0; p < PP; p += 4) {
        float4 t4 = *(const float4*)&lvec[p];
        lv[p] = t4.x; lv[p+1] = t4.y; lv[p+2] = t4.z; lv[p+3] = t4.w;
    }
    float pl[NPT][PP], po[NPT][PP];
    #pragma unroll
    for (int j = 0; j < NPT; ++j) {
        #pragma unroll
        for (int p = 0; p < PP; p += 4) {
            float4 a = *(const float4*)&pin[(h0+j)*PP + p];
            pl[j][p]   = a.x*lv[p];   pl[j][p+1] = a.y*lv[p+1];
            pl[j][p+2] = a.z*lv[p+2]; pl[j][p+3] = a.w*lv[p+3];
            float4 e4 = *(const float4*)&pout[(h0+j)*PP + p];
            po[j][p]   = e4.x; po[j][p+1] = e4.y;
            po[j][p+2] = e4.z; po[j][p+3] = e4.w;
        }
    }
    float win[NPT][6];
    #pragma unroll
    for (int j = 0; j < NPT; ++j) {
        const float2* wr = (const float2*)&Win[(h0+j)*6];
        float2 wA = wr[0], wB = wr[1], wC = wr[2];
        win[j][0]=wA.x; win[j][1]=wA.y; win[j][2]=wB.x;
        win[j][3]=wB.y; win[j][4]=wC.x; win[j][5]=wC.y;
    }
    float4 woa = *(const float4*)&Wout[h0];        // Wout[0][h0..h0+3]
    float4 wob = *(const float4*)&Wout[HID + h0];  // Wout[1][h0..h0+3]

    float4 sd4 = *(const float4*)&stdv[h0];
    float dd[NPT], sg[NPT];
    {
        float sdv[4] = { sd4.x, sd4.y, sd4.z, sd4.w };
        #pragma unroll
        for (int j = 0; j < NPT; ++j) {
            float sig = 1.f / (1.f + expf(-sdv[j]));
            float tau = sig * 0.03f + 0.02f;
            dd[j] = expf(-DTV / tau);
            sg[j] = DTV / (tau * 0.002f);
        }
    }
    const float DECAY_R = expf(-2.5f);
    const float DTE     = DTV * DECAY_R;

    // ---------------- state ----------------
    float mem[NPT], rr[NPT], ss[NPT];
    float pre[NPT], rlin[NPT], slin[NPT];
    float palin[PP], yalin = 0.f, yblin = 0.f;
    #pragma unroll
    for (int j = 0; j < NPT; ++j) { mem[j]=0.f; rr[j]=0.f; ss[j]=0.f; }
    #pragma unroll
    for (int p = 0; p < PP; ++p) palin[p] = 0.f;

    const float2* x2 = (const float2*)x;
    float4 nz = *(const float4*)&noise[h0];           // t = 0
    float2 xa = x2[0], xb = x2[1], xc = x2[2];

    float uu[16];
    #pragma unroll
    for (int p = 0; p < 16; ++p) uu[p] = 0.f;

    for (int t = 0; t <= TT; ++t) {
        const int par = t & 1;

        // ---- top of step: block sum of deposited parts; publish tag t ----
        float bs = 0.f;
        if (t > 0) {
            if (lane < 18) {
                bs = (part[0][lane] + part[1][lane])
                   + (part[2][lane] + part[3][lane]);
            }
            if (wave == 0) {
                if (lane < 16) {
                    if (t < TT) {      // nobody polls t==TT
                        union { float f; unsigned u; } cv; cv.f = bs;
                        unsigned long long pk =
                            ((unsigned long long)(unsigned)t << 32)
                          | (unsigned long long)cv.u;
                        AS(&slots[(size_t)(par*KB + b)*SLOTW + lane], pk);
                    }
                } else if (lane < 18) {
                    // block-private y partial of y[t-1] (plain store)
                    ypart[(size_t)b*(2*TT) + (t-1)*2 + (lane-16)] = bs;
                }
            }
        }

        // ---- visibility window: u-independent work for step t ----
        if (t < TT) {
            float nzv[4] = { nz.x, nz.y, nz.z, nz.w };
            #pragma unroll
            for (int j = 0; j < NPT; ++j) {
                float xw = win[j][0]*xa.x + win[j][1]*xa.y
                         + win[j][2]*xb.x + win[j][3]*xb.y
                         + win[j][4]*xc.x + win[j][5]*xc.y;
                float rst = (mem[j] - THRV > 0.f) ? THRV : 0.f;
                pre[j]  = BETA*mem[j] + xw + nzv[j] / 10.0f - rst;
                rlin[j] = dd[j]*rr[j] + DTE*ss[j];
                slin[j] = DECAY_R*ss[j];
            }
            #pragma unroll
            for (int p = 0; p < PP; ++p)
                palin[p] = (po[0][p]*rlin[0] + po[1][p]*rlin[1])
                         + (po[2][p]*rlin[2] + po[3][p]*rlin[3]);
            yalin = (woa.x*rlin[0]+woa.y*rlin[1]) + (woa.z*rlin[2]+woa.w*rlin[3]);
            yblin = (wob.x*rlin[0]+wob.y*rlin[1]) + (wob.z*rlin[2]+wob.w*rlin[3]);
        }

        // ---- poll 3 remote blocks' tagged lines (agent scope, proven path) ----
        if (t > 0 && t < TT) {
            const size_t sb = (size_t)par * KB;
            float f0 = 0.f, f1 = 0.f, f2 = 0.f;
            if (lane < 16) {
                const unsigned long long* pa_ = &slots[(sb + rbA)*SLOTW + lane];
                const unsigned long long* pb_ = &slots[(sb + rbB)*SLOTW + lane];
                const unsigned long long* pc_ = &slots[(sb + rbC)*SLOTW + lane];
                unsigned long long va, vb, vc;
                int sp = 0;
                do {
                    va = AL(pa_); vb = AL(pb_); vc = AL(pc_);
                } while ((((unsigned)(va >> 32) != (unsigned)t) |
                          ((unsigned)(vb >> 32) != (unsigned)t) |
                          ((unsigned)(vc >> 32) != (unsigned)t)) &&
                         ++sp < (1 << 20));
                union { unsigned u; float f; } c0, c1, c2;
                c0.u = (unsigned)va; c1.u = (unsigned)vb; c2.u = (unsigned)vc;
                f0 = c0.f; f1 = c1.f; f2 = c2.f;
            }
            // canonical block-order tree: (B0+B1)+(B2+B3), identical everywhere
            float total = (b < 2) ? ((bs + f0) + (f1 + f2))
                                  : ((f0 + f1) + (f2 + bs));
            if (lane < 16) ubuf[wave][lane] = total;
            float4 u0 = *(const float4*)&ubuf[wave][0];
            float4 u1 = *(const float4*)&ubuf[wave][4];
            float4 u2 = *(const float4*)&ubuf[wave][8];
            float4 u3 = *(const float4*)&ubuf[wave][12];
            uu[0]=u0.x; uu[1]=u0.y; uu[2]=u0.z; uu[3]=u0.w;
            uu[4]=u1.x; uu[5]=u1.y; uu[6]=u1.z; uu[7]=u1.w;
            uu[8]=u2.x; uu[9]=u2.y; uu[10]=u2.z; uu[11]=u2.w;
            uu[12]=u3.x; uu[13]=u3.y; uu[14]=u3.z; uu[15]=u3.w;
        }

        // ---- update + next projection + butterfly + deposit ----
        if (t < TT) {
            // prefetch next step's inputs (overlaps update + next publish)
            if (t < TT - 1) {
                const int tn = t + 1;
                nz = *(const float4*)&noise[tn * HID + h0];
                xa = x2[tn*3]; xb = x2[tn*3+1]; xc = x2[tn*3+2];
            }

            float rs[NPT];
            #pragma unroll
            for (int j = 0; j < NPT; ++j) {
                float ra  = pl[j][0]*uu[0];
                float rb_ = pl[j][8]*uu[8];
                #pragma unroll
                for (int p = 1; p < 8; ++p) {
                    ra  += pl[j][p]*uu[p];
                    rb_ += pl[j][p+8]*uu[p+8];
                }
                mem[j] = pre[j] + (ra + rb_);
                bool spk = (mem[j] - THRV > 0.f);
                float rspk = spk ? DTV*sg[j] : 0.f;
                ss[j] = slin[j] + (spk ? sg[j] : 0.f);
                rr[j] = rlin[j] + rspk;
                rs[j] = rspk;
            }
            float pa[18];
            #pragma unroll
            for (int p = 0; p < PP; ++p)
                pa[p] = palin[p] + ((po[0][p]*rs[0] + po[1][p]*rs[1])
                                 +  (po[2][p]*rs[2] + po[3][p]*rs[3]));
            pa[16] = yalin + ((woa.x*rs[0]+woa.y*rs[1]) + (woa.z*rs[2]+woa.w*rs[3]));
            pa[17] = yblin + ((wob.x*rs[0]+wob.y*rs[1]) + (wob.z*rs[2]+wob.w*rs[3]));

            // reduce-scatter butterfly: lane ends with u[lane&15] / y[lane&1]
            float a1[8], yv;
            #pragma unroll
            for (int k = 0; k < 8; ++k) {
                float keep = lb0 ? pa[2*k+1] : pa[2*k];
                float send = lb0 ? pa[2*k]   : pa[2*k+1];
                a1[k] = keep + dppx<0xB1>(send);          // xor1 (DPP)
            }
            {
                float keep = lb0 ? pa[17] : pa[16];
                float send = lb0 ? pa[16] : pa[17];
                yv = keep + dppx<0xB1>(send);
            }
            float a2[4];
            #pragma unroll
            for (int k = 0; k < 4; ++k) {
                float keep = lb1 ? a1[2*k+1] : a1[2*k];
                float send = lb1 ? a1[2*k]   : a1[2*k+1];
                a2[k] = keep + dppx<0x4E>(send);          // xor2 (DPP)
            }
            yv += dppx<0x4E>(yv);
            float a3[2];
            #pragma unroll
            for (int k = 0; k < 2; ++k) {
                float keep = lb2 ? a2[2*k+1] : a2[2*k];
                float send = lb2 ? a2[2*k]   : a2[2*k+1];
                a3[k] = keep + __shfl_xor(send, 4, 64);   // xor4 (DS)
            }
            yv += __shfl_xor(yv, 4, 64);
            float uv;
            {
                float keep = lb3 ? a3[1] : a3[0];
                float send = lb3 ? a3[0] : a3[1];
                uv = keep + dppx<0x128>(send);            // xor8 (DPP row_ror:8)
            }
            yv += dppx<0x128>(yv);
            uv += __shfl_xor(uv, 16, 64);                 // xor16 (DS)
            uv += __shfl_xor(uv, 32, 64);                 // xor32 (DS)
            yv += __shfl_xor(yv, 16, 64);
            yv += __shfl_xor(yv, 32, 64);

            if (lane < 18) part[wave][lane] = (lane < 16) ? uv : yv;
            __syncthreads();   // deposit->read separation; poll next iter >> read time
        }
    }
}

__global__ void ysum_kernel(const float* __restrict__ yp, float* __restrict__ out) {
    int i = blockIdx.x * blockDim.x + threadIdx.x;
    if (i < 2 * TT) {
        float a = yp[i];
        float b = yp[2*TT + i];
        float c = yp[2*2*TT + i];
        float d = yp[3*2*TT + i];
        out[i] = (a + b) + (c + d);    // canonical (B0+B1)+(B2+B3)
    }
}

extern "C" void kernel_launch(void* const* d_in, const int* in_sizes, int n_in,
                              void* d_out, int out_size, void* d_ws, size_t ws_size,
                              hipStream_t stream)
{
    const float* x     = (const float*)d_in[0];
    const float* noise = (const float*)d_in[1];
    const float* Win   = (const float*)d_in[2];
    const float* Wout  = (const float*)d_in[3];
    const float* pin   = (const float*)d_in[4];
    const float* pout  = (const float*)d_in[5];
    const float* l     = (const float*)d_in[6];
    const float* stdv  = (const float*)d_in[7];
    float* out = (float*)d_out;
    unsigned long long* slots = (unsigned long long*)d_ws;       // 2*4*32*8 = 2 KB
    float* ypart = (float*)((char*)d_ws + 4096);                 // 4 * 2000 floats

    hipLaunchKernelGGL(snn_kernel, dim3(KB), dim3(NTHREADS), 0, stream,
                       x, noise, Win, Wout, pin, pout, l, stdv,
                       ypart, slots);
    hipLaunchKernelGGL(ysum_kernel, dim3((2*TT + 255)/256), dim3(256), 0, stream,
                       ypart, out);
}